// Round 12
// baseline (478.607 us; speedup 1.0000x reference)
//
#include <hip/hip_runtime.h>
#include <hip/hip_bf16.h>

// Problem constants
#define B_   2
#define N_   50000
#define FD_  13
#define E_   250000
#define M_   128
#define H_   128

typedef __attribute__((ext_vector_type(8))) short  short8;
typedef __attribute__((ext_vector_type(8))) __bf16 bf16x8;
typedef __attribute__((ext_vector_type(4))) float  f32x4;
typedef __attribute__((ext_vector_type(8))) unsigned short ushort8;

// ws layout: [msg bf16 4*E*128][hist][sorted][frags]  (~261 MB, proven available)
#define MSG_BYTES  (4ull * E_ * 128 * 2)          // 256,000,000
#define HIST_BYTES (4ull * N_ * 4)                // 800,000
#define SORT_BYTES (4ull * E_ * 4)                // 4,000,000
// fragment offsets in ushort units (each frag = 64 lanes * 8 ush = 1KB)
#define OFF_EW1 0u
#define OFF_WW1 8192u
#define OFF_EW2 16384u
#define OFF_XW1 32768u
#define OFF_YW1 40960u
#define OFF_XW2 49152u
#define OFF_NW1 65536u    // 72 frags (K=288 reordered: [agg_h 0..127|agg_w 128..255|z 256..268|pad])
#define OFF_NW2 102400u

__device__ __forceinline__ float bf2f(unsigned short u) {
    unsigned int v = ((unsigned int)u) << 16;
    return __builtin_bit_cast(float, v);
}
// HW bf16 convert on gfx950.
__device__ __forceinline__ unsigned short f2bf(float f) {
    __bf16 h = (__bf16)f;
    return __builtin_bit_cast(unsigned short, h);
}
// no -ffast-math in harness: avoid IEEE divide -> v_rcp_f32
__device__ __forceinline__ float tanh_fast(float x) {
    float e = __expf(x + x);
    float r = __builtin_amdgcn_rcpf(e + 1.0f);
    return __builtin_fmaf(-2.0f, r, 1.0f);         // 1 - 2/(e+1)
}
__device__ __forceinline__ float sigmoid_fast(float x) {
    return __builtin_amdgcn_rcpf(1.0f + __expf(-x));
}
__device__ __forceinline__ f32x4 mfma16(short8 a, short8 b, f32x4 c) {
    return __builtin_amdgcn_mfma_f32_16x16x32_bf16(
        __builtin_bit_cast(bf16x8, a), __builtin_bit_cast(bf16x8, b), c, 0, 0, 0);
}

// ---------------------------------------------------------------------------
// Prep: fp32 weights -> bf16 B-fragment-major.
// Fragment (ks,nt): lane l holds B[k = ks*32 + (l>>4)*8 + j][n = nt*16 + (l&15)]
// ---------------------------------------------------------------------------
__global__ void prep_kernel(const float* __restrict__ ew1, const float* __restrict__ ww1,
                            const float* __restrict__ ew2, const float* __restrict__ xw1,
                            const float* __restrict__ yw1, const float* __restrict__ xw2,
                            const float* __restrict__ nw1, const float* __restrict__ nw2,
                            unsigned short* __restrict__ fb) {
    int m = blockIdx.y, f = blockIdx.x, l = threadIdx.x;
    const float* src; int K, Nn, KS; unsigned int off;
    switch (m) {
        case 0: src = ew1; K = 34;  Nn = 128; KS = 2; off = OFF_EW1; break;
        case 1: src = ww1; K = 34;  Nn = 128; KS = 2; off = OFF_WW1; break;
        case 2: src = ew2; K = 128; Nn = 128; KS = 4; off = OFF_EW2; break;
        case 3: src = xw1; K = 34;  Nn = 128; KS = 2; off = OFF_XW1; break;
        case 4: src = yw1; K = 34;  Nn = 128; KS = 2; off = OFF_YW1; break;
        case 5: src = xw2; K = 128; Nn = 128; KS = 4; off = OFF_XW2; break;
        case 6: src = nw1; K = 269; Nn = 128; KS = 9; off = OFF_NW1; break;
        default: src = nw2; K = 128; Nn = 13; KS = 4; off = OFF_NW2; break;
    }
    int NT = (Nn + 15) / 16;
    if (f >= KS * NT) return;
    int ks = f / NT, nt = f % NT;
    int n = nt * 16 + (l & 15);
    unsigned short* dst = fb + off + ((unsigned int)f * 64u + (unsigned int)l) * 8u;
    #pragma unroll
    for (int j = 0; j < 8; j++) {
        int k = ks * 32 + ((l >> 4) * 8) + j;
        int kk = k; bool valid = (k < K) && (n < Nn);
        if (m == 6) {
            if (k < 256)      kk = k + 13;
            else if (k < 269) kk = k - 256;
            else              valid = false;
            valid = valid && (n < Nn);
        }
        dst[j] = valid ? f2bf(src[kk * Nn + n]) : (unsigned short)0;
    }
}

// ---------------------------------------------------------------------------
// Counting sort of edges by target, per pass p (p&1=batch, p>>1=set).
// ---------------------------------------------------------------------------
__global__ void hist_kernel(const int* __restrict__ ehh, const int* __restrict__ eww,
                            int* __restrict__ hist) {
    int p = blockIdx.y, idx = blockIdx.x * 256 + threadIdx.x;
    if (idx >= E_) return;
    const int* eg = ((p >> 1) ? eww : ehh) + (size_t)(p & 1) * 2 * E_;
    atomicAdd(&hist[p * N_ + eg[E_ + idx]], 1);
}

// chunk = 52 ints (208 B, 16B-aligned) per thread; values register-cached.
__global__ void scan_kernel(int* __restrict__ hist) {
    __shared__ int part[1024];
    const int p = blockIdx.x, tid = threadIdx.x;
    int* h = hist + p * N_;
    const int lo = tid * 52;
    int cnt = N_ - lo; if (cnt < 0) cnt = 0; if (cnt > 52) cnt = 52;
    int v[52];
    int sum = 0;
    if (cnt == 52) {
        const int4* src = (const int4*)(h + lo);
        #pragma unroll
        for (int i = 0; i < 13; i++) {
            int4 t = src[i];
            v[4*i] = t.x; v[4*i+1] = t.y; v[4*i+2] = t.z; v[4*i+3] = t.w;
        }
        #pragma unroll
        for (int i = 0; i < 52; i++) sum += v[i];
    } else {
        for (int i = 0; i < cnt; i++) sum += h[lo + i];
    }
    part[tid] = sum;
    __syncthreads();
    for (int off = 1; off < 1024; off <<= 1) {
        int t = (tid >= off) ? part[tid - off] : 0;
        __syncthreads();
        part[tid] += t;
        __syncthreads();
    }
    int excl = (tid == 0) ? 0 : part[tid - 1];
    if (cnt == 52) {
        int4* dst = (int4*)(h + lo);
        #pragma unroll
        for (int i = 0; i < 13; i++) {
            int4 o;
            o.x = excl; excl += v[4*i];
            o.y = excl; excl += v[4*i+1];
            o.z = excl; excl += v[4*i+2];
            o.w = excl; excl += v[4*i+3];
            dst[i] = o;
        }
    } else {
        for (int i = 0; i < cnt; i++) { int t = h[lo + i]; h[lo + i] = excl; excl += t; }
    }
}

__global__ void scatter_kernel(const int* __restrict__ ehh, const int* __restrict__ eww,
                               int* __restrict__ hist, int* __restrict__ sorted) {
    int p = blockIdx.y, idx = blockIdx.x * 256 + threadIdx.x;
    if (idx >= E_) return;
    const int* eg = ((p >> 1) ? eww : ehh) + (size_t)(p & 1) * 2 * E_;
    int t = eg[E_ + idx];
    int pos = atomicAdd(&hist[p * N_ + t], 1);   // after: hist[t] = end offset
    sorted[p * E_ + pos] = idx;
}

// ---------------------------------------------------------------------------
// Edge kernel (R11, frozen): 128 target-sorted edges per block, 256 threads.
// 3 blocks/CU keeps concurrent msg-write footprint at 3 MB/XCD < 4 MB L2
// (4 blocks/CU caused partial-line eviction: +100 MB WRITE, +73 MB FETCH).
// ---------------------------------------------------------------------------
__launch_bounds__(256, 3)
__global__ void edge_kernel_msg(const float* __restrict__ z,
                                const int* __restrict__ ehh, const int* __restrict__ eww,
                                const int* __restrict__ sorted,
                                const unsigned short* __restrict__ fb,
                                unsigned short* __restrict__ msg,
                                const float* __restrict__ eb1, const float* __restrict__ wb1,
                                const float* __restrict__ ww2, const float* __restrict__ wb2,
                                const float* __restrict__ eb2,
                                const float* __restrict__ xb1, const float* __restrict__ yb1,
                                const float* __restrict__ yw2, const float* __restrict__ yb2,
                                const float* __restrict__ xb2) {
    __shared__ alignas(16) unsigned short Abuf[128][48];   // cols 0..39 used
    __shared__ alignas(16) unsigned short Hbuf[128][136];
    __shared__ float w_acc[128];   // gate partial sums, then sigmoid in place

    const int tid  = threadIdx.x;
    const int lane = tid & 63, wv = tid >> 6, quad = lane >> 4, c = lane & 15;
    const int pass = blockIdx.y, b = pass & 1, set = pass >> 1;
    const int ebase = blockIdx.x * 128;

    const int* eg = (set ? eww : ehh) + (size_t)b * 2 * E_;
    const float* zb = z + (size_t)b * N_ * FD_;
    unsigned short* msgp = msg + (size_t)pass * E_ * 128;

    const short8* Fm1 = (const short8*)(fb + (set ? OFF_XW1 : OFF_EW1));
    const short8* Fw1 = (const short8*)(fb + (set ? OFF_YW1 : OFF_WW1));
    const short8* Fm2 = (const short8*)(fb + (set ? OFF_XW2 : OFF_EW2));
    const float* B1m = set ? xb1 : eb1;
    const float* B1w = set ? yb1 : wb1;
    const float* B2m = set ? xb2 : eb2;
    const float* Wv2 = set ? yw2 : ww2;
    const float wbias = (set ? yb2 : wb2)[0];

    const int nt0 = wv * 2;
    short8 bm[2][2], bw[2][2], b2f[2][4];
    float bias1m[2], bias1w[2], bias2m[2], w2v[2];
    #pragma unroll
    for (int i = 0; i < 2; i++) {
        int nt = nt0 + i, n = nt * 16 + c;
        #pragma unroll
        for (int ks = 0; ks < 2; ks++) { bm[i][ks] = Fm1[(ks * 8 + nt) * 64 + lane];
                                         bw[i][ks] = Fw1[(ks * 8 + nt) * 64 + lane]; }
        #pragma unroll
        for (int ks = 0; ks < 4; ks++) { b2f[i][ks] = Fm2[(ks * 8 + nt) * 64 + lane]; }
        bias1m[i] = B1m[n]; bias1w[i] = B1w[n];
        bias2m[i] = B2m[n]; w2v[i] = Wv2[n];
    }

    // ---- Stage edge features (threads 0..127, one sorted edge each) ----
    if (tid < 128) {
        const int e = tid;
        int sp = ebase + e; if (sp >= E_) sp = E_ - 1;
        int idx = sorted[(size_t)pass * E_ + sp];
        int s = eg[idx], t = eg[E_ + idx];
        w_acc[e] = 0.0f;
        const float* zs = zb + (size_t)s * 13;
        const float* zt = zb + (size_t)t * 13;
        float fs[13], ft[13];
        __builtin_memcpy(fs, zs, 13 * sizeof(float));
        __builtin_memcpy(ft, zt, 13 * sizeof(float));
        float d0 = fs[0] - ft[0], d1 = fs[1] - ft[1], d2 = fs[2] - ft[2];
        float dist = d0 * d0 + d1 * d1 + d2 * d2;
        float c0 = fs[4] * ft[5] - fs[5] * ft[4];
        float c1 = fs[5] * ft[3] - fs[3] * ft[5];
        float c2 = fs[3] * ft[4] - fs[4] * ft[3];
        float vxn = sqrtf(c0 * c0 + c1 * c1 + c2 * c2);
        unsigned short row[40];
        #pragma unroll
        for (int j = 0; j < 13; j++) { row[j] = f2bf(fs[j]); row[13 + j] = f2bf(ft[j]); }
        row[26] = f2bf(d0); row[27] = f2bf(d1); row[28] = f2bf(d2); row[29] = f2bf(dist);
        row[30] = f2bf(c0); row[31] = f2bf(c1); row[32] = f2bf(c2); row[33] = f2bf(vxn);
        #pragma unroll
        for (int j = 34; j < 40; j++) row[j] = 0;
        #pragma unroll
        for (int v = 0; v < 5; v++) {
            short8 sv;
            #pragma unroll
            for (int j = 0; j < 8; j++) sv[j] = (short)row[v * 8 + j];
            *((short8*)&Abuf[e][v * 8]) = sv;
        }
    }
    __syncthreads();

    // ---- Layer 1: hidden = tanh(inp @ W1 + b1) for m-MLP and gate-MLP ----
    #pragma unroll 1
    for (int rt = 0; rt < 8; rt++) {
        const unsigned short* ar = &Abuf[rt * 16 + c][0];
        short8 a0 = *((const short8*)(ar + quad * 8));
        short8 a1 = {};
        if (quad == 0) a1 = *((const short8*)(ar + 32));   // cols 32..39 (34+ zero)
        float wpart[4] = {0.f, 0.f, 0.f, 0.f};
        #pragma unroll
        for (int i = 0; i < 2; i++) {
            f32x4 accm = {bias1m[i], bias1m[i], bias1m[i], bias1m[i]};
            f32x4 accw = {bias1w[i], bias1w[i], bias1w[i], bias1w[i]};
            accm = mfma16(a0, bm[i][0], accm);
            accm = mfma16(a1, bm[i][1], accm);
            accw = mfma16(a0, bw[i][0], accw);
            accw = mfma16(a1, bw[i][1], accw);
            int n = (nt0 + i) * 16 + c;
            #pragma unroll
            for (int r = 0; r < 4; r++) {
                Hbuf[rt * 16 + quad * 4 + r][n] = f2bf(tanh_fast(accm[r]));
                wpart[r] += tanh_fast(accw[r]) * w2v[i];
            }
        }
        #pragma unroll
        for (int r = 0; r < 4; r++) {
            float v = wpart[r];
            v += __shfl_xor(v, 1); v += __shfl_xor(v, 2);
            v += __shfl_xor(v, 4); v += __shfl_xor(v, 8);
            if (c == r) atomicAdd(&w_acc[rt * 16 + quad * 4 + r], v);
        }
    }
    __syncthreads();
    if (tid < 128) w_acc[tid] = sigmoid_fast(w_acc[tid] + wbias);
    __syncthreads();

    // ---- Layer 2: plain bf16 stores of gated messages at sorted positions ----
    #pragma unroll 1
    for (int rt = 0; rt < 8; rt++) {
        const unsigned short* hr = &Hbuf[rt * 16 + c][0];
        short8 h0 = *((const short8*)(hr + quad * 8));
        short8 h1 = *((const short8*)(hr + 32 + quad * 8));
        short8 h2 = *((const short8*)(hr + 64 + quad * 8));
        short8 h3 = *((const short8*)(hr + 96 + quad * 8));
        const int elq = rt * 16 + quad * 4;
        const float g0 = w_acc[elq + 0], g1 = w_acc[elq + 1];
        const float g2 = w_acc[elq + 2], g3 = w_acc[elq + 3];
        #pragma unroll
        for (int i = 0; i < 2; i++) {
            f32x4 acc = {bias2m[i], bias2m[i], bias2m[i], bias2m[i]};
            acc = mfma16(h0, b2f[i][0], acc);
            acc = mfma16(h1, b2f[i][1], acc);
            acc = mfma16(h2, b2f[i][2], acc);
            acc = mfma16(h3, b2f[i][3], acc);
            const int n = (nt0 + i) * 16 + c;
            const float gv[4] = {g0, g1, g2, g3};
            #pragma unroll
            for (int r = 0; r < 4; r++) {
                int e = elq + r;
                if (ebase + e < E_)
                    msgp[(size_t)(ebase + e) * 128 + n] = f2bf(acc[r] * gv[r]);
            }
        }
    }
}

// ---------------------------------------------------------------------------
// Node kernel: 1024 threads = 16 waves = 16 nodes per block.
// WAVE-PER-NODE gather: lane owns 2 columns (4B coalesced loads, 256B/row
// per wave), uniform trip count within the wave (no max-of-4 divergence),
// unroll 4 -> 4 outstanding loads; LB(1024,8) -> 32 waves/CU.
// K layout: [agg_h(128) | agg_w(128) | z(13) | pad -> 288]
// ---------------------------------------------------------------------------
__launch_bounds__(1024, 8)
__global__ void node_fused(const float* __restrict__ z,
                           const unsigned short* __restrict__ msg,
                           const int* __restrict__ hist,
                           const unsigned short* __restrict__ fb,
                           const float* __restrict__ nb1,
                           const float* __restrict__ nb2,
                           float* __restrict__ out) {
    __shared__ alignas(16) unsigned short Abuf[16][296];
    __shared__ alignas(16) unsigned short Hbuf[16][136];

    const int tid  = threadIdx.x;
    const int lane = tid & 63, wv = tid >> 6, quad = lane >> 4, c = lane & 15;
    const int g0 = blockIdx.x * 16;

    // ---- gather: wave wv handles node g0+wv, both sets ----
    {
        const int nl = wv;
        const int g = g0 + nl;                 // grid exact: g < B_*N_
        const int b = (g >= N_) ? 1 : 0;
        const int t = g - b * N_;
        #pragma unroll
        for (int s = 0; s < 2; s++) {
            const int p = s * 2 + b;
            const int end = hist[p * N_ + t];
            int j = (t > 0) ? hist[p * N_ + t - 1] : 0;
            const unsigned short* mp = msg + (size_t)p * E_ * 128 + lane * 2;
            float a0 = 0.f, a1 = 0.f;
            for (; j + 4 <= end; j += 4) {
                unsigned int u0 = *(const unsigned int*)(mp + (size_t)(j + 0) * 128);
                unsigned int u1 = *(const unsigned int*)(mp + (size_t)(j + 1) * 128);
                unsigned int u2 = *(const unsigned int*)(mp + (size_t)(j + 2) * 128);
                unsigned int u3 = *(const unsigned int*)(mp + (size_t)(j + 3) * 128);
                a0 += (bf2f((unsigned short)(u0 & 0xffffu)) + bf2f((unsigned short)(u1 & 0xffffu)))
                    + (bf2f((unsigned short)(u2 & 0xffffu)) + bf2f((unsigned short)(u3 & 0xffffu)));
                a1 += (bf2f((unsigned short)(u0 >> 16)) + bf2f((unsigned short)(u1 >> 16)))
                    + (bf2f((unsigned short)(u2 >> 16)) + bf2f((unsigned short)(u3 >> 16)));
            }
            for (; j < end; j++) {
                unsigned int u = *(const unsigned int*)(mp + (size_t)j * 128);
                a0 += bf2f((unsigned short)(u & 0xffffu));
                a1 += bf2f((unsigned short)(u >> 16));
            }
            unsigned int w = (unsigned int)f2bf(a0) | ((unsigned int)f2bf(a1) << 16);
            *(unsigned int*)&Abuf[nl][s * 128 + lane * 2] = w;
        }
    }
    for (int j = tid; j < 16 * 13; j += 1024) {       // z -> cols 256..268
        int nl = j / 13, k = j % 13;
        Abuf[nl][256 + k] = f2bf(z[(size_t)(g0 + nl) * 13 + k]);
    }
    for (int j = tid; j < 16 * 19; j += 1024) {       // pad cols 269..287
        int nl = j / 19, k = j % 19;
        Abuf[nl][269 + k] = 0;
    }
    __syncthreads();

    // ---- Layer 1: 8 waves, one 16-wide n-tile each ----
    if (wv < 8) {
        const short8* F1 = (const short8*)(fb + OFF_NW1);
        const int nt = wv;
        const float b1 = nb1[nt * 16 + c];
        f32x4 acc = {b1, b1, b1, b1};
        #pragma unroll
        for (int ks = 0; ks < 9; ks++) {
            short8 a = *((const short8*)(&Abuf[c][0] + ks * 32 + quad * 8));
            acc = mfma16(a, F1[(ks * 8 + nt) * 64 + lane], acc);
        }
        #pragma unroll
        for (int r = 0; r < 4; r++)
            Hbuf[quad * 4 + r][nt * 16 + c] = f2bf(tanh_fast(acc[r]));
    }
    __syncthreads();

    // ---- Layer 2: wave 0 only (16x13 output) ----
    if (wv == 0) {
        const short8* F2 = (const short8*)(fb + OFF_NW2);
        const float bias2 = (c < 13) ? nb2[c] : 0.0f;
        f32x4 acc = {bias2, bias2, bias2, bias2};
        #pragma unroll
        for (int ks = 0; ks < 4; ks++) {
            short8 h = *((const short8*)(&Hbuf[c][0] + ks * 32 + quad * 8));
            acc = mfma16(h, F2[ks * 64 + lane], acc);
        }
        #pragma unroll
        for (int r = 0; r < 4; r++) {
            int g = g0 + quad * 4 + r;
            if (c < 13) out[(size_t)g * 13 + c] = acc[r];
        }
    }
}

// ---------------------------------------------------------------------------
extern "C" void kernel_launch(void* const* d_in, const int* in_sizes, int n_in,
                              void* d_out, int out_size, void* d_ws, size_t ws_size,
                              hipStream_t stream) {
    const float* z   = (const float*)d_in[0];
    const int* ehh   = (const int*)d_in[1];
    const int* eww   = (const int*)d_in[2];
    const float* ew1 = (const float*)d_in[3];
    const float* eb1 = (const float*)d_in[4];
    const float* ew2 = (const float*)d_in[5];
    const float* eb2 = (const float*)d_in[6];
    const float* ww1 = (const float*)d_in[7];
    const float* wb1 = (const float*)d_in[8];
    const float* ww2 = (const float*)d_in[9];
    const float* wb2 = (const float*)d_in[10];
    const float* xw1 = (const float*)d_in[11];
    const float* xb1 = (const float*)d_in[12];
    const float* xw2 = (const float*)d_in[13];
    const float* xb2 = (const float*)d_in[14];
    const float* yw1 = (const float*)d_in[15];
    const float* yb1 = (const float*)d_in[16];
    const float* yw2 = (const float*)d_in[17];
    const float* yb2 = (const float*)d_in[18];
    const float* nw1 = (const float*)d_in[19];
    const float* nb1 = (const float*)d_in[20];
    const float* nw2 = (const float*)d_in[21];
    const float* nb2 = (const float*)d_in[22];

    unsigned short* msg = (unsigned short*)d_ws;
    int* hist   = (int*)((char*)d_ws + MSG_BYTES);
    int* sorted = (int*)((char*)d_ws + MSG_BYTES + HIST_BYTES);
    unsigned short* frag = (unsigned short*)((char*)d_ws + MSG_BYTES + HIST_BYTES + SORT_BYTES);

    hipMemsetAsync(hist, 0, HIST_BYTES, stream);
    prep_kernel<<<dim3(72, 8), 64, 0, stream>>>(ew1, ww1, ew2, xw1, yw1, xw2, nw1, nw2, frag);
    hist_kernel<<<dim3((E_ + 255) / 256, 4), 256, 0, stream>>>(ehh, eww, hist);
    scan_kernel<<<4, 1024, 0, stream>>>(hist);
    scatter_kernel<<<dim3((E_ + 255) / 256, 4), 256, 0, stream>>>(ehh, eww, hist, sorted);
    edge_kernel_msg<<<dim3((E_ + 127) / 128, 4), 256, 0, stream>>>(
        z, ehh, eww, sorted, frag, msg,
        eb1, wb1, ww2, wb2, eb2,
        xb1, yb1, yw2, yb2, xb2);
    node_fused<<<(B_ * N_) / 16, 1024, 0, stream>>>(
        z, msg, hist, frag, nb1, nb2, (float*)d_out);
}

// Round 13
// 441.167 us; speedup vs baseline: 1.0849x; 1.0849x over previous
//
#include <hip/hip_runtime.h>
#include <hip/hip_bf16.h>

// Problem constants
#define B_   2
#define N_   50000
#define FD_  13
#define E_   250000
#define M_   128
#define H_   128

typedef __attribute__((ext_vector_type(8))) short  short8;
typedef __attribute__((ext_vector_type(8))) __bf16 bf16x8;
typedef __attribute__((ext_vector_type(4))) float  f32x4;
typedef __attribute__((ext_vector_type(8))) unsigned short ushort8;

// ws layout: [msg bf16 4*E*128][hist][sorted(packed st)][frags]  (~261 MB)
#define MSG_BYTES  (4ull * E_ * 128 * 2)          // 256,000,000
#define HIST_BYTES (4ull * N_ * 4)                // 800,000
#define SORT_BYTES (4ull * E_ * 4)                // 4,000,000
// fragment offsets in ushort units (each frag = 64 lanes * 8 ush = 1KB)
#define OFF_EW1 0u
#define OFF_WW1 8192u
#define OFF_EW2 16384u
#define OFF_XW1 32768u
#define OFF_YW1 40960u
#define OFF_XW2 49152u
#define OFF_NW1 65536u    // 72 frags (K=288 reordered: [agg_h 0..127|agg_w 128..255|z 256..268|pad])
#define OFF_NW2 102400u

__device__ __forceinline__ float bf2f(unsigned short u) {
    unsigned int v = ((unsigned int)u) << 16;
    return __builtin_bit_cast(float, v);
}
// HW bf16 convert on gfx950.
__device__ __forceinline__ unsigned short f2bf(float f) {
    __bf16 h = (__bf16)f;
    return __builtin_bit_cast(unsigned short, h);
}
// no -ffast-math in harness: avoid IEEE divide -> v_rcp_f32
__device__ __forceinline__ float tanh_fast(float x) {
    float e = __expf(x + x);
    float r = __builtin_amdgcn_rcpf(e + 1.0f);
    return __builtin_fmaf(-2.0f, r, 1.0f);         // 1 - 2/(e+1)
}
__device__ __forceinline__ float sigmoid_fast(float x) {
    return __builtin_amdgcn_rcpf(1.0f + __expf(-x));
}
__device__ __forceinline__ f32x4 mfma16(short8 a, short8 b, f32x4 c) {
    return __builtin_amdgcn_mfma_f32_16x16x32_bf16(
        __builtin_bit_cast(bf16x8, a), __builtin_bit_cast(bf16x8, b), c, 0, 0, 0);
}

// ---------------------------------------------------------------------------
// Prep: fp32 weights -> bf16 B-fragment-major.
// Fragment (ks,nt): lane l holds B[k = ks*32 + (l>>4)*8 + j][n = nt*16 + (l&15)]
// ---------------------------------------------------------------------------
__global__ void prep_kernel(const float* __restrict__ ew1, const float* __restrict__ ww1,
                            const float* __restrict__ ew2, const float* __restrict__ xw1,
                            const float* __restrict__ yw1, const float* __restrict__ xw2,
                            const float* __restrict__ nw1, const float* __restrict__ nw2,
                            unsigned short* __restrict__ fb) {
    int m = blockIdx.y, f = blockIdx.x, l = threadIdx.x;
    const float* src; int K, Nn, KS; unsigned int off;
    switch (m) {
        case 0: src = ew1; K = 34;  Nn = 128; KS = 2; off = OFF_EW1; break;
        case 1: src = ww1; K = 34;  Nn = 128; KS = 2; off = OFF_WW1; break;
        case 2: src = ew2; K = 128; Nn = 128; KS = 4; off = OFF_EW2; break;
        case 3: src = xw1; K = 34;  Nn = 128; KS = 2; off = OFF_XW1; break;
        case 4: src = yw1; K = 34;  Nn = 128; KS = 2; off = OFF_YW1; break;
        case 5: src = xw2; K = 128; Nn = 128; KS = 4; off = OFF_XW2; break;
        case 6: src = nw1; K = 269; Nn = 128; KS = 9; off = OFF_NW1; break;
        default: src = nw2; K = 128; Nn = 13; KS = 4; off = OFF_NW2; break;
    }
    int NT = (Nn + 15) / 16;
    if (f >= KS * NT) return;
    int ks = f / NT, nt = f % NT;
    int n = nt * 16 + (l & 15);
    unsigned short* dst = fb + off + ((unsigned int)f * 64u + (unsigned int)l) * 8u;
    #pragma unroll
    for (int j = 0; j < 8; j++) {
        int k = ks * 32 + ((l >> 4) * 8) + j;
        int kk = k; bool valid = (k < K) && (n < Nn);
        if (m == 6) {
            if (k < 256)      kk = k + 13;
            else if (k < 269) kk = k - 256;
            else              valid = false;
            valid = valid && (n < Nn);
        }
        dst[j] = valid ? f2bf(src[kk * Nn + n]) : (unsigned short)0;
    }
}

// ---------------------------------------------------------------------------
// Counting sort of edges by target, per pass p (p&1=batch, p>>1=set).
// ---------------------------------------------------------------------------
__global__ void hist_kernel(const int* __restrict__ ehh, const int* __restrict__ eww,
                            int* __restrict__ hist) {
    int p = blockIdx.y, idx = blockIdx.x * 256 + threadIdx.x;
    if (idx >= E_) return;
    const int* eg = ((p >> 1) ? eww : ehh) + (size_t)(p & 1) * 2 * E_;
    atomicAdd(&hist[p * N_ + eg[E_ + idx]], 1);
}

// chunk = 52 ints (208 B, 16B-aligned) per thread; values register-cached.
__global__ void scan_kernel(int* __restrict__ hist) {
    __shared__ int part[1024];
    const int p = blockIdx.x, tid = threadIdx.x;
    int* h = hist + p * N_;
    const int lo = tid * 52;
    int cnt = N_ - lo; if (cnt < 0) cnt = 0; if (cnt > 52) cnt = 52;
    int v[52];
    int sum = 0;
    if (cnt == 52) {
        const int4* src = (const int4*)(h + lo);
        #pragma unroll
        for (int i = 0; i < 13; i++) {
            int4 t = src[i];
            v[4*i] = t.x; v[4*i+1] = t.y; v[4*i+2] = t.z; v[4*i+3] = t.w;
        }
        #pragma unroll
        for (int i = 0; i < 52; i++) sum += v[i];
    } else {
        for (int i = 0; i < cnt; i++) sum += h[lo + i];
    }
    part[tid] = sum;
    __syncthreads();
    for (int off = 1; off < 1024; off <<= 1) {
        int t = (tid >= off) ? part[tid - off] : 0;
        __syncthreads();
        part[tid] += t;
        __syncthreads();
    }
    int excl = (tid == 0) ? 0 : part[tid - 1];
    if (cnt == 52) {
        int4* dst = (int4*)(h + lo);
        #pragma unroll
        for (int i = 0; i < 13; i++) {
            int4 o;
            o.x = excl; excl += v[4*i];
            o.y = excl; excl += v[4*i+1];
            o.z = excl; excl += v[4*i+2];
            o.w = excl; excl += v[4*i+3];
            dst[i] = o;
        }
    } else {
        for (int i = 0; i < cnt; i++) { int t = h[lo + i]; h[lo + i] = excl; excl += t; }
    }
}

// Writes PACKED endpoints (s | t<<16; N=50000 < 2^16) at the sorted position,
// absorbing the random eg[] lookups here (coalesced reads) so the edge kernel
// reads one sequential uint per edge.
__global__ void scatter_kernel(const int* __restrict__ ehh, const int* __restrict__ eww,
                               int* __restrict__ hist, unsigned int* __restrict__ sorted) {
    int p = blockIdx.y, idx = blockIdx.x * 256 + threadIdx.x;
    if (idx >= E_) return;
    const int* eg = ((p >> 1) ? eww : ehh) + (size_t)(p & 1) * 2 * E_;
    int s = eg[idx];
    int t = eg[E_ + idx];
    int pos = atomicAdd(&hist[p * N_ + t], 1);   // after: hist[t] = end offset
    sorted[(size_t)p * E_ + pos] = (unsigned int)s | ((unsigned int)t << 16);
}

// ---------------------------------------------------------------------------
// Edge kernel (R11 structure, frozen): 128 target-sorted edges per block,
// 256 threads, 3 blocks/CU (concurrent msg-write footprint 3 MB/XCD < 4 MB L2;
// 4 blocks/CU caused partial-line eviction: +100 MB WRITE, +73 MB FETCH).
// Staging now reads packed (s,t) sequentially instead of 2 random eg reads.
// ---------------------------------------------------------------------------
__launch_bounds__(256, 3)
__global__ void edge_kernel_msg(const float* __restrict__ z,
                                const unsigned int* __restrict__ sorted,
                                const unsigned short* __restrict__ fb,
                                unsigned short* __restrict__ msg,
                                const float* __restrict__ eb1, const float* __restrict__ wb1,
                                const float* __restrict__ ww2, const float* __restrict__ wb2,
                                const float* __restrict__ eb2,
                                const float* __restrict__ xb1, const float* __restrict__ yb1,
                                const float* __restrict__ yw2, const float* __restrict__ yb2,
                                const float* __restrict__ xb2) {
    __shared__ alignas(16) unsigned short Abuf[128][48];   // cols 0..39 used
    __shared__ alignas(16) unsigned short Hbuf[128][136];
    __shared__ float w_acc[128];   // gate partial sums, then sigmoid in place

    const int tid  = threadIdx.x;
    const int lane = tid & 63, wv = tid >> 6, quad = lane >> 4, c = lane & 15;
    const int pass = blockIdx.y, b = pass & 1, set = pass >> 1;
    const int ebase = blockIdx.x * 128;

    const float* zb = z + (size_t)b * N_ * FD_;
    unsigned short* msgp = msg + (size_t)pass * E_ * 128;

    const short8* Fm1 = (const short8*)(fb + (set ? OFF_XW1 : OFF_EW1));
    const short8* Fw1 = (const short8*)(fb + (set ? OFF_YW1 : OFF_WW1));
    const short8* Fm2 = (const short8*)(fb + (set ? OFF_XW2 : OFF_EW2));
    const float* B1m = set ? xb1 : eb1;
    const float* B1w = set ? yb1 : wb1;
    const float* B2m = set ? xb2 : eb2;
    const float* Wv2 = set ? yw2 : ww2;
    const float wbias = (set ? yb2 : wb2)[0];

    const int nt0 = wv * 2;
    short8 bm[2][2], bw[2][2], b2f[2][4];
    float bias1m[2], bias1w[2], bias2m[2], w2v[2];
    #pragma unroll
    for (int i = 0; i < 2; i++) {
        int nt = nt0 + i, n = nt * 16 + c;
        #pragma unroll
        for (int ks = 0; ks < 2; ks++) { bm[i][ks] = Fm1[(ks * 8 + nt) * 64 + lane];
                                         bw[i][ks] = Fw1[(ks * 8 + nt) * 64 + lane]; }
        #pragma unroll
        for (int ks = 0; ks < 4; ks++) { b2f[i][ks] = Fm2[(ks * 8 + nt) * 64 + lane]; }
        bias1m[i] = B1m[n]; bias1w[i] = B1w[n];
        bias2m[i] = B2m[n]; w2v[i] = Wv2[n];
    }

    // ---- Stage edge features (threads 0..127, one sorted edge each) ----
    if (tid < 128) {
        const int e = tid;
        int sp = ebase + e; if (sp >= E_) sp = E_ - 1;
        unsigned int st = sorted[(size_t)pass * E_ + sp];
        int s = (int)(st & 0xffffu), t = (int)(st >> 16);
        w_acc[e] = 0.0f;
        const float* zs = zb + (size_t)s * 13;
        const float* zt = zb + (size_t)t * 13;
        float fs[13], ft[13];
        __builtin_memcpy(fs, zs, 13 * sizeof(float));
        __builtin_memcpy(ft, zt, 13 * sizeof(float));
        float d0 = fs[0] - ft[0], d1 = fs[1] - ft[1], d2 = fs[2] - ft[2];
        float dist = d0 * d0 + d1 * d1 + d2 * d2;
        float c0 = fs[4] * ft[5] - fs[5] * ft[4];
        float c1 = fs[5] * ft[3] - fs[3] * ft[5];
        float c2 = fs[3] * ft[4] - fs[4] * ft[3];
        float vxn = sqrtf(c0 * c0 + c1 * c1 + c2 * c2);
        unsigned short row[40];
        #pragma unroll
        for (int j = 0; j < 13; j++) { row[j] = f2bf(fs[j]); row[13 + j] = f2bf(ft[j]); }
        row[26] = f2bf(d0); row[27] = f2bf(d1); row[28] = f2bf(d2); row[29] = f2bf(dist);
        row[30] = f2bf(c0); row[31] = f2bf(c1); row[32] = f2bf(c2); row[33] = f2bf(vxn);
        #pragma unroll
        for (int j = 34; j < 40; j++) row[j] = 0;
        #pragma unroll
        for (int v = 0; v < 5; v++) {
            short8 sv;
            #pragma unroll
            for (int j = 0; j < 8; j++) sv[j] = (short)row[v * 8 + j];
            *((short8*)&Abuf[e][v * 8]) = sv;
        }
    }
    __syncthreads();

    // ---- Layer 1: hidden = tanh(inp @ W1 + b1) for m-MLP and gate-MLP ----
    #pragma unroll 1
    for (int rt = 0; rt < 8; rt++) {
        const unsigned short* ar = &Abuf[rt * 16 + c][0];
        short8 a0 = *((const short8*)(ar + quad * 8));
        short8 a1 = {};
        if (quad == 0) a1 = *((const short8*)(ar + 32));   // cols 32..39 (34+ zero)
        float wpart[4] = {0.f, 0.f, 0.f, 0.f};
        #pragma unroll
        for (int i = 0; i < 2; i++) {
            f32x4 accm = {bias1m[i], bias1m[i], bias1m[i], bias1m[i]};
            f32x4 accw = {bias1w[i], bias1w[i], bias1w[i], bias1w[i]};
            accm = mfma16(a0, bm[i][0], accm);
            accm = mfma16(a1, bm[i][1], accm);
            accw = mfma16(a0, bw[i][0], accw);
            accw = mfma16(a1, bw[i][1], accw);
            int n = (nt0 + i) * 16 + c;
            #pragma unroll
            for (int r = 0; r < 4; r++) {
                Hbuf[rt * 16 + quad * 4 + r][n] = f2bf(tanh_fast(accm[r]));
                wpart[r] += tanh_fast(accw[r]) * w2v[i];
            }
        }
        #pragma unroll
        for (int r = 0; r < 4; r++) {
            float v = wpart[r];
            v += __shfl_xor(v, 1); v += __shfl_xor(v, 2);
            v += __shfl_xor(v, 4); v += __shfl_xor(v, 8);
            if (c == r) atomicAdd(&w_acc[rt * 16 + quad * 4 + r], v);
        }
    }
    __syncthreads();
    if (tid < 128) w_acc[tid] = sigmoid_fast(w_acc[tid] + wbias);
    __syncthreads();

    // ---- Layer 2: plain bf16 stores of gated messages at sorted positions ----
    #pragma unroll 1
    for (int rt = 0; rt < 8; rt++) {
        const unsigned short* hr = &Hbuf[rt * 16 + c][0];
        short8 h0 = *((const short8*)(hr + quad * 8));
        short8 h1 = *((const short8*)(hr + 32 + quad * 8));
        short8 h2 = *((const short8*)(hr + 64 + quad * 8));
        short8 h3 = *((const short8*)(hr + 96 + quad * 8));
        const int elq = rt * 16 + quad * 4;
        const float g0 = w_acc[elq + 0], g1 = w_acc[elq + 1];
        const float g2 = w_acc[elq + 2], g3 = w_acc[elq + 3];
        #pragma unroll
        for (int i = 0; i < 2; i++) {
            f32x4 acc = {bias2m[i], bias2m[i], bias2m[i], bias2m[i]};
            acc = mfma16(h0, b2f[i][0], acc);
            acc = mfma16(h1, b2f[i][1], acc);
            acc = mfma16(h2, b2f[i][2], acc);
            acc = mfma16(h3, b2f[i][3], acc);
            const int n = (nt0 + i) * 16 + c;
            const float gv[4] = {g0, g1, g2, g3};
            #pragma unroll
            for (int r = 0; r < 4; r++) {
                int e = elq + r;
                if (ebase + e < E_)
                    msgp[(size_t)(ebase + e) * 128 + n] = f2bf(acc[r] * gv[r]);
            }
        }
    }
}

// ---------------------------------------------------------------------------
// Fused node kernel (R8/R11 proven structure): 16 nodes/block, 256 threads,
// 16 threads/node with 16B loads; unroll 8 -> up to 8 outstanding 16B
// loads/lane (MLP-bound gather; R12 showed occupancy can't substitute for
// per-lane width).
// K layout: [agg_h(128) | agg_w(128) | z(13) | pad -> 288]
// ---------------------------------------------------------------------------
__launch_bounds__(256, 4)
__global__ void node_fused(const float* __restrict__ z,
                           const unsigned short* __restrict__ msg,
                           const int* __restrict__ hist,
                           const unsigned short* __restrict__ fb,
                           const float* __restrict__ nb1,
                           const float* __restrict__ nb2,
                           float* __restrict__ out) {
    __shared__ alignas(16) unsigned short Abuf[16][296];
    __shared__ alignas(16) unsigned short Hbuf[16][136];

    const int tid  = threadIdx.x;
    const int lane = tid & 63, wv = tid >> 6, quad = lane >> 4, c = lane & 15;
    const int g0 = blockIdx.x * 16;

    // ---- staging: CSR gather-reduce, unroll 8 ----
    {
        const int nl = tid >> 4;        // node 0..15
        const int part = tid & 15;      // col group: cols part*8 .. part*8+7
        const int g = g0 + nl;
        const int b = (g >= N_) ? 1 : 0;
        const int t = g - b * N_;
        #pragma unroll
        for (int s = 0; s < 2; s++) {
            const int p = s * 2 + b;
            const int end   = hist[p * N_ + t];
            const int start = (t > 0) ? hist[p * N_ + t - 1] : 0;
            float acc[8];
            #pragma unroll
            for (int k = 0; k < 8; k++) acc[k] = 0.f;
            const unsigned short* mp = msg + (size_t)p * E_ * 128 + part * 8;
            int j = start;
            for (; j + 8 <= end; j += 8) {
                ushort8 m[8];
                #pragma unroll
                for (int q = 0; q < 8; q++)
                    m[q] = *(const ushort8*)(mp + (size_t)(j + q) * 128);
                #pragma unroll
                for (int k = 0; k < 8; k++)
                    acc[k] += ((bf2f(m[0][k]) + bf2f(m[1][k])) + (bf2f(m[2][k]) + bf2f(m[3][k])))
                            + ((bf2f(m[4][k]) + bf2f(m[5][k])) + (bf2f(m[6][k]) + bf2f(m[7][k])));
            }
            for (; j + 2 <= end; j += 2) {
                ushort8 m0 = *(const ushort8*)(mp + (size_t)(j + 0) * 128);
                ushort8 m1 = *(const ushort8*)(mp + (size_t)(j + 1) * 128);
                #pragma unroll
                for (int k = 0; k < 8; k++) acc[k] += bf2f(m0[k]) + bf2f(m1[k]);
            }
            for (; j < end; j++) {
                ushort8 m = *(const ushort8*)(mp + (size_t)j * 128);
                #pragma unroll
                for (int k = 0; k < 8; k++) acc[k] += bf2f(m[k]);
            }
            ushort8 u;
            #pragma unroll
            for (int k = 0; k < 8; k++) u[k] = f2bf(acc[k]);
            *((ushort8*)&Abuf[nl][s * 128 + part * 8]) = u;
        }
    }
    for (int j = tid; j < 16 * 13; j += 256) {       // z -> cols 256..268
        int nl = j / 13, k = j % 13;
        Abuf[nl][256 + k] = f2bf(z[(size_t)(g0 + nl) * 13 + k]);
    }
    for (int j = tid; j < 16 * 19; j += 256) {       // pad cols 269..287
        int nl = j / 19, k = j % 19;
        Abuf[nl][269 + k] = 0;
    }
    __syncthreads();

    // ---- Layer 1: one 16-row tile; wave wv owns n-tiles wv*2, wv*2+1 ----
    {
        const short8* F1 = (const short8*)(fb + OFF_NW1);
        const int nt0 = wv * 2;
        const float b1a = nb1[nt0 * 16 + c];
        const float b1b = nb1[(nt0 + 1) * 16 + c];
        f32x4 acc0 = {b1a, b1a, b1a, b1a};
        f32x4 acc1 = {b1b, b1b, b1b, b1b};
        #pragma unroll
        for (int ks = 0; ks < 9; ks++) {
            short8 a = *((const short8*)(&Abuf[c][0] + ks * 32 + quad * 8));
            acc0 = mfma16(a, F1[(ks * 8 + nt0) * 64 + lane], acc0);
            acc1 = mfma16(a, F1[(ks * 8 + nt0 + 1) * 64 + lane], acc1);
        }
        #pragma unroll
        for (int r = 0; r < 4; r++) {
            Hbuf[quad * 4 + r][nt0 * 16 + c]       = f2bf(tanh_fast(acc0[r]));
            Hbuf[quad * 4 + r][(nt0 + 1) * 16 + c] = f2bf(tanh_fast(acc1[r]));
        }
    }
    __syncthreads();

    // ---- Layer 2: wave 0 only (16x13 output) ----
    if (wv == 0) {
        const short8* F2 = (const short8*)(fb + OFF_NW2);
        const float bias2 = (c < 13) ? nb2[c] : 0.0f;
        f32x4 acc = {bias2, bias2, bias2, bias2};
        #pragma unroll
        for (int ks = 0; ks < 4; ks++) {
            short8 h = *((const short8*)(&Hbuf[c][0] + ks * 32 + quad * 8));
            acc = mfma16(h, F2[ks * 64 + lane], acc);
        }
        #pragma unroll
        for (int r = 0; r < 4; r++) {
            int g = g0 + quad * 4 + r;
            if (c < 13) out[(size_t)g * 13 + c] = acc[r];
        }
    }
}

// ---------------------------------------------------------------------------
extern "C" void kernel_launch(void* const* d_in, const int* in_sizes, int n_in,
                              void* d_out, int out_size, void* d_ws, size_t ws_size,
                              hipStream_t stream) {
    const float* z   = (const float*)d_in[0];
    const int* ehh   = (const int*)d_in[1];
    const int* eww   = (const int*)d_in[2];
    const float* ew1 = (const float*)d_in[3];
    const float* eb1 = (const float*)d_in[4];
    const float* ew2 = (const float*)d_in[5];
    const float* eb2 = (const float*)d_in[6];
    const float* ww1 = (const float*)d_in[7];
    const float* wb1 = (const float*)d_in[8];
    const float* ww2 = (const float*)d_in[9];
    const float* wb2 = (const float*)d_in[10];
    const float* xw1 = (const float*)d_in[11];
    const float* xb1 = (const float*)d_in[12];
    const float* xw2 = (const float*)d_in[13];
    const float* xb2 = (const float*)d_in[14];
    const float* yw1 = (const float*)d_in[15];
    const float* yb1 = (const float*)d_in[16];
    const float* yw2 = (const float*)d_in[17];
    const float* yb2 = (const float*)d_in[18];
    const float* nw1 = (const float*)d_in[19];
    const float* nb1 = (const float*)d_in[20];
    const float* nw2 = (const float*)d_in[21];
    const float* nb2 = (const float*)d_in[22];

    unsigned short* msg = (unsigned short*)d_ws;
    int* hist   = (int*)((char*)d_ws + MSG_BYTES);
    unsigned int* sorted = (unsigned int*)((char*)d_ws + MSG_BYTES + HIST_BYTES);
    unsigned short* frag = (unsigned short*)((char*)d_ws + MSG_BYTES + HIST_BYTES + SORT_BYTES);

    hipMemsetAsync(hist, 0, HIST_BYTES, stream);
    prep_kernel<<<dim3(72, 8), 64, 0, stream>>>(ew1, ww1, ew2, xw1, yw1, xw2, nw1, nw2, frag);
    hist_kernel<<<dim3((E_ + 255) / 256, 4), 256, 0, stream>>>(ehh, eww, hist);
    scan_kernel<<<4, 1024, 0, stream>>>(hist);
    scatter_kernel<<<dim3((E_ + 255) / 256, 4), 256, 0, stream>>>(ehh, eww, hist, sorted);
    edge_kernel_msg<<<dim3((E_ + 127) / 128, 4), 256, 0, stream>>>(
        z, sorted, frag, msg,
        eb1, wb1, ww2, wb2, eb2,
        xb1, yb1, yw2, yb2, xb2);
    node_fused<<<(B_ * N_) / 16, 256, 0, stream>>>(
        z, msg, hist, frag, nb1, nb2, (float*)d_out);
}